// Round 8
// baseline (303.920 us; speedup 1.0000x reference)
//
#include <hip/hip_runtime.h>

typedef __bf16 bf16;
typedef __attribute__((ext_vector_type(4))) __bf16 bf16x4;
typedef __attribute__((ext_vector_type(8))) __bf16 bf16x8;
typedef __attribute__((ext_vector_type(4))) float f32x4;
typedef __attribute__((ext_vector_type(4))) unsigned int u32x4;

#define B_ 4
#define S_ 2048
#define D_ 1024
#define H_ 16
#define HD_ 64

#define GLB(p) ((const __attribute__((address_space(1))) void*)(p))
#define LDS(p) ((__attribute__((address_space(3))) void*)(p))

// ---------------- pass 0a: weight transpose+convert (K,N)fp32 -> (N,K)bf16 --
__global__ __launch_bounds__(256) void transpose_cvt(
    const float* __restrict__ W0, const float* __restrict__ W1,
    const float* __restrict__ W2, const float* __restrict__ W3,
    bf16* __restrict__ T0, bf16* __restrict__ T1,
    bf16* __restrict__ T2, bf16* __restrict__ T3)
{
    __shared__ float tile[32][33];
    int z = blockIdx.z;
    const float* W = (z == 0) ? W0 : (z == 1) ? W1 : (z == 2) ? W2 : W3;
    bf16*        T = (z == 0) ? T0 : (z == 1) ? T1 : (z == 2) ? T2 : T3;
    int bx = blockIdx.x * 32, by = blockIdx.y * 32;
    int tx = threadIdx.x & 31, ty = threadIdx.x >> 5;
    #pragma unroll
    for (int j = 0; j < 32; j += 8)
        tile[ty + j][tx] = W[(size_t)(by + ty + j) * D_ + bx + tx];
    __syncthreads();
    #pragma unroll
    for (int j = 0; j < 32; j += 8)
        T[(size_t)(bx + ty + j) * D_ + by + tx] = (bf16)tile[tx][ty + j];
}

// ---------------- pass 0b: X fp32 -> bf16 ----------------
__global__ __launch_bounds__(256) void cvt_x(
    const float* __restrict__ X, bf16* __restrict__ Xb)
{
    size_t i = ((size_t)blockIdx.x * 256 + threadIdx.x) * 8;
    f32x4 a = *(const f32x4*)(X + i);
    f32x4 b = *(const f32x4*)(X + i + 4);
    bf16x8 v;
    #pragma unroll
    for (int j = 0; j < 4; ++j) { v[j] = (bf16)a[j]; v[4 + j] = (bf16)b[j]; }
    *(bf16x8*)(Xb + i) = v;
}

// ---------------- pass 1: fused QKV projection GEMM ----------------
// C(8192x1024) = Xb(bf16) @ W, WT(N,K) bf16 in ws. 128x128 tile, BK=32,
// global_load_lds width=16 staging.
// z in {0,1} (Q,K): TRANSPOSED mfma (b,a) -> lane holds fixed s, 4 consecutive
//   hd per reg quad -> packed bf16x4 stores to [b,h,s,hd]. Q pre-scaled
//   log2(e)/8 (exp2-domain softmax).
// z == 2 (V): original orientation -> packed bf16x4 (4 consecutive s) stores
//   to V^T [b,h,hd,s].
__global__ __launch_bounds__(256) void qkv_gemm(
    const bf16* __restrict__ Xb,
    const bf16* __restrict__ WqT, const bf16* __restrict__ WkT, const bf16* __restrict__ WvT,
    const float* __restrict__ bq, const float* __restrict__ bk, const float* __restrict__ bv,
    bf16* __restrict__ Qo, bf16* __restrict__ Ko, bf16* __restrict__ Vo)
{
    const int z = blockIdx.z;
    const bf16*  WT   = (z == 0) ? WqT : (z == 1) ? WkT : WvT;
    const float* bias = (z == 0) ? bq  : (z == 1) ? bk  : bv;
    bf16*        out  = (z == 0) ? Qo  : (z == 1) ? Ko  : Vo;
    const float scale = (z == 0) ? 0.18033688011112042f : 1.0f;

    __shared__ bf16 As[128 * 32];
    __shared__ bf16 Bs[128 * 32];

    const int t = threadIdx.x;
    const int lid = t & 63, w = t >> 6;
    const int wm = w & 1, wn = w >> 1;
    const int lrow = lid & 15, quad = lid >> 4;
    const int m0 = blockIdx.y * 128, n0 = blockIdx.x * 128;

    const bf16* Ag = Xb + (size_t)m0 * D_;
    const bf16* Bg = WT + (size_t)n0 * D_;

    const int row0 = t >> 2, k80 = (t & 3) << 3;
    const int row1 = (t + 256) >> 2;

    f32x4 acc[4][4] = {};

    if (z != 2) {
        // ---- transposed path (Q, K) ----
        for (int k0 = 0; k0 < D_; k0 += 32) {
            __syncthreads();
            __builtin_amdgcn_global_load_lds(GLB(Ag + (size_t)row0 * D_ + k0 + k80),
                                             LDS(As + t * 8), 16, 0, 0);
            __builtin_amdgcn_global_load_lds(GLB(Bg + (size_t)row0 * D_ + k0 + k80),
                                             LDS(Bs + t * 8), 16, 0, 0);
            __builtin_amdgcn_global_load_lds(GLB(Ag + (size_t)row1 * D_ + k0 + k80),
                                             LDS(As + t * 8 + 2048), 16, 0, 0);
            __builtin_amdgcn_global_load_lds(GLB(Bg + (size_t)row1 * D_ + k0 + k80),
                                             LDS(Bs + t * 8 + 2048), 16, 0, 0);
            __syncthreads();
            bf16x8 a[4], b[4];
            #pragma unroll
            for (int mb = 0; mb < 4; ++mb)
                a[mb] = *(const bf16x8*)(As + (wm * 64 + mb * 16 + lrow) * 32 + quad * 8);
            #pragma unroll
            for (int nb = 0; nb < 4; ++nb)
                b[nb] = *(const bf16x8*)(Bs + (wn * 64 + nb * 16 + lrow) * 32 + quad * 8);
            #pragma unroll
            for (int mb = 0; mb < 4; ++mb)
                #pragma unroll
                for (int nb = 0; nb < 4; ++nb)
                    acc[mb][nb] = __builtin_amdgcn_mfma_f32_16x16x32_bf16(b[nb], a[mb], acc[mb][nb], 0, 0, 0);
        }
        // epilogue: col=lane&15 -> s, reg r -> hd (4 consecutive)
        #pragma unroll
        for (int mb = 0; mb < 4; ++mb) {
            int gm = m0 + wm * 64 + mb * 16 + lrow;
            int bb = gm >> 11, s = gm & 2047;
            #pragma unroll
            for (int nb = 0; nb < 4; ++nb) {
                int gn0 = n0 + wn * 64 + nb * 16 + quad * 4;
                int h = gn0 >> 6, hd0 = gn0 & 63;
                f32x4 bv4 = *(const f32x4*)(bias + gn0);
                bf16x4 pk;
                #pragma unroll
                for (int r = 0; r < 4; ++r)
                    pk[r] = (bf16)((acc[mb][nb][r] + bv4[r]) * scale);
                *(bf16x4*)(out + (((size_t)(bb * H_ + h)) * S_ + s) * HD_ + hd0) = pk;
            }
        }
    } else {
        // ---- original path (V) ----
        for (int k0 = 0; k0 < D_; k0 += 32) {
            __syncthreads();
            __builtin_amdgcn_global_load_lds(GLB(Ag + (size_t)row0 * D_ + k0 + k80),
                                             LDS(As + t * 8), 16, 0, 0);
            __builtin_amdgcn_global_load_lds(GLB(Bg + (size_t)row0 * D_ + k0 + k80),
                                             LDS(Bs + t * 8), 16, 0, 0);
            __builtin_amdgcn_global_load_lds(GLB(Ag + (size_t)row1 * D_ + k0 + k80),
                                             LDS(As + t * 8 + 2048), 16, 0, 0);
            __builtin_amdgcn_global_load_lds(GLB(Bg + (size_t)row1 * D_ + k0 + k80),
                                             LDS(Bs + t * 8 + 2048), 16, 0, 0);
            __syncthreads();
            bf16x8 a[4], b[4];
            #pragma unroll
            for (int mb = 0; mb < 4; ++mb)
                a[mb] = *(const bf16x8*)(As + (wm * 64 + mb * 16 + lrow) * 32 + quad * 8);
            #pragma unroll
            for (int nb = 0; nb < 4; ++nb)
                b[nb] = *(const bf16x8*)(Bs + (wn * 64 + nb * 16 + lrow) * 32 + quad * 8);
            #pragma unroll
            for (int mb = 0; mb < 4; ++mb)
                #pragma unroll
                for (int nb = 0; nb < 4; ++nb)
                    acc[mb][nb] = __builtin_amdgcn_mfma_f32_16x16x32_bf16(a[mb], b[nb], acc[mb][nb], 0, 0, 0);
        }
        // epilogue: col -> hd, reg r -> 4 consecutive s; V^T [b,h,hd,s]
        #pragma unroll
        for (int mb = 0; mb < 4; ++mb) {
            #pragma unroll
            for (int nb = 0; nb < 4; ++nb) {
                int gn = n0 + wn * 64 + nb * 16 + lrow;
                float bsv = bias[gn];
                int h = gn >> 6, hd = gn & 63;
                int gm0 = m0 + wm * 64 + mb * 16 + quad * 4;
                int bb = gm0 >> 11, s0 = gm0 & 2047;
                bf16x4 pk;
                #pragma unroll
                for (int r = 0; r < 4; ++r)
                    pk[r] = (bf16)(acc[mb][nb][r] + bsv);
                *(bf16x4*)(out + (((size_t)(bb * H_ + h)) * HD_ + hd) * S_ + s0) = pk;
            }
        }
    }
}

// ---------------- pass 2: causal flash attention (S-transposed scheme) -----
// 64-query tiles (32 qtiles). Each block: pair (31-p, p) -> constant 33
// key-tile units. XCD swizzle: bh = (bx&7) + 8*(by&7) so all 16 blocks of a
// (b,h) share lin%8 -> same XCD L2 holds that head's K/V.
// 4 waves x 16 queries. S^T = mfma(K_frag, Q_frag); softmax in-lane + 2
// shuffles; P packed b64; O^T = mfma(V^T_frag, P_frag). V^T: [b,h,hd,s].
__global__ __launch_bounds__(256) void attn_fwd(
    const bf16* __restrict__ Q, const bf16* __restrict__ K,
    const bf16* __restrict__ Vt, bf16* __restrict__ O)
{
    __shared__ bf16 Ks[64 * 72];        // [key][hd], stride 72
    __shared__ bf16 Vs[64 * 72];        // [hd][key], staged from V^T
    __shared__ bf16 Ps[4 * 16 * 72];    // per-wave P [query][key], stride 72

    const int p  = (blockIdx.x >> 3) + ((blockIdx.y >> 3) << 1);   // [0,16)
    const int bh = (blockIdx.x & 7) + ((blockIdx.y & 7) << 3);     // [0,64)
    const int t = threadIdx.x, lid = t & 63, w = t >> 6;
    const int lrow = lid & 15, quad = lid >> 4;
    const int b = bh >> 4, h = bh & 15;

    #pragma unroll 1
    for (int half = 0; half < 2; ++half) {
        const int qtile = half ? p : (31 - p);
        const int qbase = qtile * 64;

        // Q fragments (B-operand): lane n=query=lrow, k=hd in-lane
        const bf16* Qp = Q + ((size_t)bh * S_ + qbase + w * 16) * HD_;
        bf16x8 qf[2];
        #pragma unroll
        for (int ks = 0; ks < 2; ++ks)
            qf[ks] = *(const bf16x8*)(Qp + lrow * HD_ + ks * 32 + quad * 8);

        f32x4 o_acc[4] = {};              // O^T: [hd-block], col=query
        float m_i = -3.0e4f, l_i = 0.0f;

        for (int kt = 0; kt <= qtile; ++kt) {
            const bf16* Kp = K  + ((size_t)bh * S_ + kt * 64) * HD_;
            const bf16* Vp = Vt + ((size_t)bh * HD_) * S_ + kt * 64;
            __syncthreads();
            #pragma unroll
            for (int i = 0; i < 2; ++i) {
                int c = t + i * 256;
                int row = c >> 3, c8 = (c & 7) << 3;   // row: key for K, hd for V
                *(u32x4*)(Ks + row * 72 + c8) = *(const u32x4*)(Kp + (size_t)row * HD_ + c8);
                *(u32x4*)(Vs + row * 72 + c8) = *(const u32x4*)(Vp + (size_t)row * S_ + c8);
            }
            __syncthreads();

            // S^T = K Q^T: lane: query=lrow, key=nb*16+quad*4+r
            f32x4 sa[4] = {};
            #pragma unroll
            for (int ks = 0; ks < 2; ++ks) {
                #pragma unroll
                for (int nb = 0; nb < 4; ++nb) {
                    bf16x8 kf = *(const bf16x8*)(Ks + (nb * 16 + lrow) * 72 + ks * 32 + quad * 8);
                    sa[nb] = __builtin_amdgcn_mfma_f32_16x16x32_bf16(kf, qf[ks], sa[nb], 0, 0, 0);
                }
            }
            if (kt == qtile) {  // diagonal tile: causal mask
                int q = qbase + w * 16 + lrow;
                #pragma unroll
                for (int nb = 0; nb < 4; ++nb) {
                    int key = kt * 64 + nb * 16 + quad * 4;
                    #pragma unroll
                    for (int r = 0; r < 4; ++r)
                        if (key + r > q) sa[nb][r] = -3.0e4f;
                }
            }

            // online softmax (exp2 domain): in-lane over 16 keys + 2 shuffles
            float p_[4][4];
            {
                float rm = sa[0][0];
                #pragma unroll
                for (int nb = 0; nb < 4; ++nb)
                    #pragma unroll
                    for (int r = 0; r < 4; ++r)
                        rm = fmaxf(rm, sa[nb][r]);
                rm = fmaxf(rm, __shfl_xor(rm, 16));
                rm = fmaxf(rm, __shfl_xor(rm, 32));
                float mnew = fmaxf(m_i, rm);
                float al = exp2f(m_i - mnew);
                m_i = mnew;
                float rs = 0.0f;
                #pragma unroll
                for (int nb = 0; nb < 4; ++nb)
                    #pragma unroll
                    for (int r = 0; r < 4; ++r) {
                        float e = exp2f(sa[nb][r] - mnew);
                        p_[nb][r] = e;
                        rs += e;
                    }
                rs += __shfl_xor(rs, 16);
                rs += __shfl_xor(rs, 32);
                l_i = l_i * al + rs;
                #pragma unroll
                for (int nb = 0; nb < 4; ++nb)
                    #pragma unroll
                    for (int r = 0; r < 4; ++r)
                        o_acc[nb][r] *= al;
            }

            // P -> LDS [query][key], packed b64 (keys quad*4..quad*4+3)
            bf16* Pw = Ps + w * 16 * 72;
            #pragma unroll
            for (int nb = 0; nb < 4; ++nb) {
                bf16x4 pk;
                #pragma unroll
                for (int r = 0; r < 4; ++r)
                    pk[r] = (bf16)p_[nb][r];
                *(bf16x4*)(Pw + lrow * 72 + nb * 16 + quad * 4) = pk;
            }
            asm volatile("s_waitcnt lgkmcnt(0)" ::: "memory");

            // O^T += V^T P^T: A=V^T[hd][key], B=P[query][key]
            #pragma unroll
            for (int ks = 0; ks < 2; ++ks) {
                bf16x8 pf = *(const bf16x8*)(Pw + lrow * 72 + ks * 32 + quad * 8);
                #pragma unroll
                for (int nb = 0; nb < 4; ++nb) {
                    bf16x8 vf = *(const bf16x8*)(Vs + (nb * 16 + lrow) * 72 + ks * 32 + quad * 8);
                    o_acc[nb] = __builtin_amdgcn_mfma_f32_16x16x32_bf16(vf, pf, o_acc[nb], 0, 0, 0);
                }
            }
        }

        // epilogue: O^T regs -> O[b,s,d]; lane: s=query fixed, 4 consecutive hd
        {
            float inv = 1.0f / l_i;
            int s = qbase + w * 16 + lrow;
            #pragma unroll
            for (int nb = 0; nb < 4; ++nb) {
                bf16x4 pk;
                #pragma unroll
                for (int r = 0; r < 4; ++r)
                    pk[r] = (bf16)(o_acc[nb][r] * inv);
                *(bf16x4*)(O + ((size_t)b * S_ + s) * D_ + h * 64 + nb * 16 + quad * 4) = pk;
            }
        }
        __syncthreads();   // protect LDS before next half re-stages
    }
}

// ---------------- pass 3: output projection GEMM (fp32 out, transposed) ----
__global__ __launch_bounds__(256) void proj_gemm(
    const bf16* __restrict__ A, const bf16* __restrict__ WpT,
    const float* __restrict__ bp, float* __restrict__ out)
{
    __shared__ bf16 As[128 * 32];
    __shared__ bf16 Bs[128 * 32];

    const int t = threadIdx.x;
    const int lid = t & 63, w = t >> 6;
    const int wm = w & 1, wn = w >> 1;
    const int lrow = lid & 15, quad = lid >> 4;
    const int m0 = blockIdx.y * 128, n0 = blockIdx.x * 128;

    const bf16* Ag = A   + (size_t)m0 * D_;
    const bf16* Bg = WpT + (size_t)n0 * D_;

    const int row0 = t >> 2, k80 = (t & 3) << 3;
    const int row1 = (t + 256) >> 2;

    f32x4 acc[4][4] = {};

    for (int k0 = 0; k0 < D_; k0 += 32) {
        __syncthreads();
        __builtin_amdgcn_global_load_lds(GLB(Ag + (size_t)row0 * D_ + k0 + k80),
                                         LDS(As + t * 8), 16, 0, 0);
        __builtin_amdgcn_global_load_lds(GLB(Bg + (size_t)row0 * D_ + k0 + k80),
                                         LDS(Bs + t * 8), 16, 0, 0);
        __builtin_amdgcn_global_load_lds(GLB(Ag + (size_t)row1 * D_ + k0 + k80),
                                         LDS(As + t * 8 + 2048), 16, 0, 0);
        __builtin_amdgcn_global_load_lds(GLB(Bg + (size_t)row1 * D_ + k0 + k80),
                                         LDS(Bs + t * 8 + 2048), 16, 0, 0);
        __syncthreads();
        bf16x8 a[4], b[4];
        #pragma unroll
        for (int mb = 0; mb < 4; ++mb)
            a[mb] = *(const bf16x8*)(As + (wm * 64 + mb * 16 + lrow) * 32 + quad * 8);
        #pragma unroll
        for (int nb = 0; nb < 4; ++nb)
            b[nb] = *(const bf16x8*)(Bs + (wn * 64 + nb * 16 + lrow) * 32 + quad * 8);
        #pragma unroll
        for (int mb = 0; mb < 4; ++mb)
            #pragma unroll
            for (int nb = 0; nb < 4; ++nb)
                acc[mb][nb] = __builtin_amdgcn_mfma_f32_16x16x32_bf16(b[nb], a[mb], acc[mb][nb], 0, 0, 0);
    }

    // epilogue: col=lane&15 -> m (row), reg r -> 4 consecutive n (cols)
    #pragma unroll
    for (int mb = 0; mb < 4; ++mb) {
        int gm = m0 + wm * 64 + mb * 16 + lrow;
        #pragma unroll
        for (int nb = 0; nb < 4; ++nb) {
            int gn0 = n0 + wn * 64 + nb * 16 + quad * 4;
            f32x4 bv4 = *(const f32x4*)(bp + gn0);
            f32x4 v = acc[mb][nb] + bv4;
            *(f32x4*)(out + (size_t)gm * D_ + gn0) = v;
        }
    }
}

// ---------------- launch ----------------
extern "C" void kernel_launch(void* const* d_in, const int* in_sizes, int n_in,
                              void* d_out, int out_size, void* d_ws, size_t ws_size,
                              hipStream_t stream)
{
    const float* x  = (const float*)d_in[0];
    const float* Wq = (const float*)d_in[1];
    const float* bq = (const float*)d_in[2];
    const float* Wk = (const float*)d_in[3];
    const float* bk = (const float*)d_in[4];
    const float* Wv = (const float*)d_in[5];
    const float* bv = (const float*)d_in[6];
    const float* Wp = (const float*)d_in[7];
    const float* bp = (const float*)d_in[8];

    bf16* ws = (bf16*)d_ws;
    const size_t WSZ = (size_t)D_ * D_;        // 1,048,576 elems
    const size_t BIG = (size_t)B_ * S_ * D_;   // 8,388,608 elems
    bf16* WqT = ws;
    bf16* WkT = WqT + WSZ;
    bf16* WvT = WkT + WSZ;
    bf16* WpT = WvT + WSZ;
    bf16* Qb  = WpT + WSZ;
    bf16* Kb  = Qb + BIG;
    bf16* Vb  = Kb + BIG;    // V^T layout [b,h,hd,s]
    bf16* Ab  = Vb + BIG;    // X(bf16) during qkv, then attention output

    transpose_cvt<<<dim3(32, 32, 4), 256, 0, stream>>>(
        Wq, Wk, Wv, Wp, WqT, WkT, WvT, WpT);

    cvt_x<<<dim3(4096), 256, 0, stream>>>(x, Ab);

    qkv_gemm<<<dim3(8, 64, 3), 256, 0, stream>>>(
        Ab, WqT, WkT, WvT, bq, bk, bv, Qb, Kb, Vb);

    attn_fwd<<<dim3(16, 64), 256, 0, stream>>>(Qb, Kb, Vb, Ab);

    proj_gemm<<<dim3(8, 64), 256, 0, stream>>>(Ab, WpT, bp, (float*)d_out);
}

// Round 9
// 302.604 us; speedup vs baseline: 1.0043x; 1.0043x over previous
//
#include <hip/hip_runtime.h>

typedef __bf16 bf16;
typedef __attribute__((ext_vector_type(4))) __bf16 bf16x4;
typedef __attribute__((ext_vector_type(8))) __bf16 bf16x8;
typedef __attribute__((ext_vector_type(4))) float f32x4;
typedef __attribute__((ext_vector_type(4))) unsigned int u32x4;

#define B_ 4
#define S_ 2048
#define D_ 1024
#define H_ 16
#define HD_ 64

#define GLB(p) ((const __attribute__((address_space(1))) void*)(p))
#define LDS(p) ((__attribute__((address_space(3))) void*)(p))

// ---------------- pass 0a: weight transpose+convert (K,N)fp32 -> (N,K)bf16 --
__global__ __launch_bounds__(256) void transpose_cvt(
    const float* __restrict__ W0, const float* __restrict__ W1,
    const float* __restrict__ W2, const float* __restrict__ W3,
    bf16* __restrict__ T0, bf16* __restrict__ T1,
    bf16* __restrict__ T2, bf16* __restrict__ T3)
{
    __shared__ float tile[32][33];
    int z = blockIdx.z;
    const float* W = (z == 0) ? W0 : (z == 1) ? W1 : (z == 2) ? W2 : W3;
    bf16*        T = (z == 0) ? T0 : (z == 1) ? T1 : (z == 2) ? T2 : T3;
    int bx = blockIdx.x * 32, by = blockIdx.y * 32;
    int tx = threadIdx.x & 31, ty = threadIdx.x >> 5;
    #pragma unroll
    for (int j = 0; j < 32; j += 8)
        tile[ty + j][tx] = W[(size_t)(by + ty + j) * D_ + bx + tx];
    __syncthreads();
    #pragma unroll
    for (int j = 0; j < 32; j += 8)
        T[(size_t)(bx + ty + j) * D_ + by + tx] = (bf16)tile[tx][ty + j];
}

// ---------------- pass 0b: X fp32 -> bf16 ----------------
__global__ __launch_bounds__(256) void cvt_x(
    const float* __restrict__ X, bf16* __restrict__ Xb)
{
    size_t i = ((size_t)blockIdx.x * 256 + threadIdx.x) * 8;
    f32x4 a = *(const f32x4*)(X + i);
    f32x4 b = *(const f32x4*)(X + i + 4);
    bf16x8 v;
    #pragma unroll
    for (int j = 0; j < 4; ++j) { v[j] = (bf16)a[j]; v[4 + j] = (bf16)b[j]; }
    *(bf16x8*)(Xb + i) = v;
}

// ---------------- pass 1: fused QKV projection GEMM ----------------
// C(8192x1024) = Xb(bf16) @ W. 128x128 tile, BK=32, global_load_lds width=16.
// ONE shared K-loop (epilogue-only branch — two K-loop copies thrash I-cache,
// R8 regression). All-z TRANSPOSED mfma(b,a): lane col (lane&15) = X-row s,
// reg quad*4+r = 4 consecutive n (hd).
//   z in {0,1} (Q,K): packed bf16x4 stores to [b,h,s,hd]; Q pre-scaled
//     log2(e)/8 (exp2-domain softmax).
//   z == 2 (V): scalar stores to V^T [b,h,hd,s] (16-lane 32B segments).
__global__ __launch_bounds__(256) void qkv_gemm(
    const bf16* __restrict__ Xb,
    const bf16* __restrict__ WqT, const bf16* __restrict__ WkT, const bf16* __restrict__ WvT,
    const float* __restrict__ bq, const float* __restrict__ bk, const float* __restrict__ bv,
    bf16* __restrict__ Qo, bf16* __restrict__ Ko, bf16* __restrict__ Vo)
{
    const int z = blockIdx.z;
    const bf16*  WT   = (z == 0) ? WqT : (z == 1) ? WkT : WvT;
    const float* bias = (z == 0) ? bq  : (z == 1) ? bk  : bv;
    bf16*        out  = (z == 0) ? Qo  : (z == 1) ? Ko  : Vo;
    const float scale = (z == 0) ? 0.18033688011112042f : 1.0f;

    __shared__ bf16 As[128 * 32];
    __shared__ bf16 Bs[128 * 32];

    const int t = threadIdx.x;
    const int lid = t & 63, w = t >> 6;
    const int wm = w & 1, wn = w >> 1;
    const int lrow = lid & 15, quad = lid >> 4;
    const int m0 = blockIdx.y * 128, n0 = blockIdx.x * 128;

    const bf16* Ag = Xb + (size_t)m0 * D_;
    const bf16* Bg = WT + (size_t)n0 * D_;

    const int row0 = t >> 2, k80 = (t & 3) << 3;
    const int row1 = (t + 256) >> 2;

    f32x4 acc[4][4] = {};

    for (int k0 = 0; k0 < D_; k0 += 32) {
        __syncthreads();
        __builtin_amdgcn_global_load_lds(GLB(Ag + (size_t)row0 * D_ + k0 + k80),
                                         LDS(As + t * 8), 16, 0, 0);
        __builtin_amdgcn_global_load_lds(GLB(Bg + (size_t)row0 * D_ + k0 + k80),
                                         LDS(Bs + t * 8), 16, 0, 0);
        __builtin_amdgcn_global_load_lds(GLB(Ag + (size_t)row1 * D_ + k0 + k80),
                                         LDS(As + t * 8 + 2048), 16, 0, 0);
        __builtin_amdgcn_global_load_lds(GLB(Bg + (size_t)row1 * D_ + k0 + k80),
                                         LDS(Bs + t * 8 + 2048), 16, 0, 0);
        __syncthreads();
        bf16x8 a[4], b[4];
        #pragma unroll
        for (int mb = 0; mb < 4; ++mb)
            a[mb] = *(const bf16x8*)(As + (wm * 64 + mb * 16 + lrow) * 32 + quad * 8);
        #pragma unroll
        for (int nb = 0; nb < 4; ++nb)
            b[nb] = *(const bf16x8*)(Bs + (wn * 64 + nb * 16 + lrow) * 32 + quad * 8);
        #pragma unroll
        for (int mb = 0; mb < 4; ++mb)
            #pragma unroll
            for (int nb = 0; nb < 4; ++nb)
                acc[mb][nb] = __builtin_amdgcn_mfma_f32_16x16x32_bf16(b[nb], a[mb], acc[mb][nb], 0, 0, 0);
    }

    if (z != 2) {
        // Q/K epilogue: lane -> fixed s, reg r -> 4 consecutive hd
        #pragma unroll
        for (int mb = 0; mb < 4; ++mb) {
            int gm = m0 + wm * 64 + mb * 16 + lrow;
            int bb = gm >> 11, s = gm & 2047;
            #pragma unroll
            for (int nb = 0; nb < 4; ++nb) {
                int gn0 = n0 + wn * 64 + nb * 16 + quad * 4;
                int h = gn0 >> 6, hd0 = gn0 & 63;
                f32x4 bv4 = *(const f32x4*)(bias + gn0);
                bf16x4 pk;
                #pragma unroll
                for (int r = 0; r < 4; ++r)
                    pk[r] = (bf16)((acc[mb][nb][r] + bv4[r]) * scale);
                *(bf16x4*)(out + (((size_t)(bb * H_ + h)) * S_ + s) * HD_ + hd0) = pk;
            }
        }
    } else {
        // V epilogue: V^T [b,h,hd,s]; hd = quad*4+r rows, s = lrow (coalesced
        // 32B per 16 lanes)
        #pragma unroll
        for (int mb = 0; mb < 4; ++mb) {
            int gm = m0 + wm * 64 + mb * 16 + lrow;
            int bb = gm >> 11, s = gm & 2047;
            #pragma unroll
            for (int nb = 0; nb < 4; ++nb) {
                int gn0 = n0 + wn * 64 + nb * 16 + quad * 4;
                int h = gn0 >> 6, hd0 = gn0 & 63;
                f32x4 bv4 = *(const f32x4*)(bias + gn0);
                #pragma unroll
                for (int r = 0; r < 4; ++r) {
                    float v = acc[mb][nb][r] + bv4[r];
                    out[(((size_t)(bb * H_ + h)) * HD_ + (hd0 + r)) * S_ + s] = (bf16)v;
                }
            }
        }
    }
}

// ---------------- pass 2: causal flash attention (S-transposed scheme) -----
// 64-query tiles (32 qtiles). Each block: pair (31-p, p) -> constant 33
// key-tile units. XCD swizzle: bh = (bx&7) + 8*(by&7) so all 16 blocks of a
// (b,h) share lin%8 -> same XCD L2 holds that head's K/V.
// 4 waves x 16 queries. S^T = mfma(K_frag, Q_frag); softmax in-lane + 2
// shuffles; P packed b64; O^T = mfma(V^T_frag, P_frag). V^T: [b,h,hd,s].
__global__ __launch_bounds__(256) void attn_fwd(
    const bf16* __restrict__ Q, const bf16* __restrict__ K,
    const bf16* __restrict__ Vt, bf16* __restrict__ O)
{
    __shared__ bf16 Ks[64 * 72];        // [key][hd], stride 72
    __shared__ bf16 Vs[64 * 72];        // [hd][key], staged from V^T
    __shared__ bf16 Ps[4 * 16 * 72];    // per-wave P [query][key], stride 72

    const int p  = (blockIdx.x >> 3) + ((blockIdx.y >> 3) << 1);   // [0,16)
    const int bh = (blockIdx.x & 7) + ((blockIdx.y & 7) << 3);     // [0,64)
    const int t = threadIdx.x, lid = t & 63, w = t >> 6;
    const int lrow = lid & 15, quad = lid >> 4;
    const int b = bh >> 4, h = bh & 15;

    #pragma unroll 1
    for (int half = 0; half < 2; ++half) {
        const int qtile = half ? p : (31 - p);
        const int qbase = qtile * 64;

        // Q fragments (B-operand): lane n=query=lrow, k=hd in-lane
        const bf16* Qp = Q + ((size_t)bh * S_ + qbase + w * 16) * HD_;
        bf16x8 qf[2];
        #pragma unroll
        for (int ks = 0; ks < 2; ++ks)
            qf[ks] = *(const bf16x8*)(Qp + lrow * HD_ + ks * 32 + quad * 8);

        f32x4 o_acc[4] = {};              // O^T: [hd-block], col=query
        float m_i = -3.0e4f, l_i = 0.0f;

        for (int kt = 0; kt <= qtile; ++kt) {
            const bf16* Kp = K  + ((size_t)bh * S_ + kt * 64) * HD_;
            const bf16* Vp = Vt + ((size_t)bh * HD_) * S_ + kt * 64;
            __syncthreads();
            #pragma unroll
            for (int i = 0; i < 2; ++i) {
                int c = t + i * 256;
                int row = c >> 3, c8 = (c & 7) << 3;   // row: key for K, hd for V
                *(u32x4*)(Ks + row * 72 + c8) = *(const u32x4*)(Kp + (size_t)row * HD_ + c8);
                *(u32x4*)(Vs + row * 72 + c8) = *(const u32x4*)(Vp + (size_t)row * S_ + c8);
            }
            __syncthreads();

            // S^T = K Q^T: lane: query=lrow, key=nb*16+quad*4+r
            f32x4 sa[4] = {};
            #pragma unroll
            for (int ks = 0; ks < 2; ++ks) {
                #pragma unroll
                for (int nb = 0; nb < 4; ++nb) {
                    bf16x8 kf = *(const bf16x8*)(Ks + (nb * 16 + lrow) * 72 + ks * 32 + quad * 8);
                    sa[nb] = __builtin_amdgcn_mfma_f32_16x16x32_bf16(kf, qf[ks], sa[nb], 0, 0, 0);
                }
            }
            if (kt == qtile) {  // diagonal tile: causal mask
                int q = qbase + w * 16 + lrow;
                #pragma unroll
                for (int nb = 0; nb < 4; ++nb) {
                    int key = kt * 64 + nb * 16 + quad * 4;
                    #pragma unroll
                    for (int r = 0; r < 4; ++r)
                        if (key + r > q) sa[nb][r] = -3.0e4f;
                }
            }

            // online softmax (exp2 domain): in-lane over 16 keys + 2 shuffles
            float p_[4][4];
            {
                float rm = sa[0][0];
                #pragma unroll
                for (int nb = 0; nb < 4; ++nb)
                    #pragma unroll
                    for (int r = 0; r < 4; ++r)
                        rm = fmaxf(rm, sa[nb][r]);
                rm = fmaxf(rm, __shfl_xor(rm, 16));
                rm = fmaxf(rm, __shfl_xor(rm, 32));
                float mnew = fmaxf(m_i, rm);
                float al = exp2f(m_i - mnew);
                m_i = mnew;
                float rs = 0.0f;
                #pragma unroll
                for (int nb = 0; nb < 4; ++nb)
                    #pragma unroll
                    for (int r = 0; r < 4; ++r) {
                        float e = exp2f(sa[nb][r] - mnew);
                        p_[nb][r] = e;
                        rs += e;
                    }
                rs += __shfl_xor(rs, 16);
                rs += __shfl_xor(rs, 32);
                l_i = l_i * al + rs;
                #pragma unroll
                for (int nb = 0; nb < 4; ++nb)
                    #pragma unroll
                    for (int r = 0; r < 4; ++r)
                        o_acc[nb][r] *= al;
            }

            // P -> LDS [query][key], packed b64 (keys quad*4..quad*4+3)
            bf16* Pw = Ps + w * 16 * 72;
            #pragma unroll
            for (int nb = 0; nb < 4; ++nb) {
                bf16x4 pk;
                #pragma unroll
                for (int r = 0; r < 4; ++r)
                    pk[r] = (bf16)p_[nb][r];
                *(bf16x4*)(Pw + lrow * 72 + nb * 16 + quad * 4) = pk;
            }
            asm volatile("s_waitcnt lgkmcnt(0)" ::: "memory");

            // O^T += V^T P^T: A=V^T[hd][key], B=P[query][key]
            #pragma unroll
            for (int ks = 0; ks < 2; ++ks) {
                bf16x8 pf = *(const bf16x8*)(Pw + lrow * 72 + ks * 32 + quad * 8);
                #pragma unroll
                for (int nb = 0; nb < 4; ++nb) {
                    bf16x8 vf = *(const bf16x8*)(Vs + (nb * 16 + lrow) * 72 + ks * 32 + quad * 8);
                    o_acc[nb] = __builtin_amdgcn_mfma_f32_16x16x32_bf16(vf, pf, o_acc[nb], 0, 0, 0);
                }
            }
        }

        // epilogue: O^T regs -> O[b,s,d]; lane: s=query fixed, 4 consecutive hd
        {
            float inv = 1.0f / l_i;
            int s = qbase + w * 16 + lrow;
            #pragma unroll
            for (int nb = 0; nb < 4; ++nb) {
                bf16x4 pk;
                #pragma unroll
                for (int r = 0; r < 4; ++r)
                    pk[r] = (bf16)(o_acc[nb][r] * inv);
                *(bf16x4*)(O + ((size_t)b * S_ + s) * D_ + h * 64 + nb * 16 + quad * 4) = pk;
            }
        }
        __syncthreads();   // protect LDS before next half re-stages
    }
}

// ---------------- pass 3: output projection GEMM (fp32 out, transposed) ----
__global__ __launch_bounds__(256) void proj_gemm(
    const bf16* __restrict__ A, const bf16* __restrict__ WpT,
    const float* __restrict__ bp, float* __restrict__ out)
{
    __shared__ bf16 As[128 * 32];
    __shared__ bf16 Bs[128 * 32];

    const int t = threadIdx.x;
    const int lid = t & 63, w = t >> 6;
    const int wm = w & 1, wn = w >> 1;
    const int lrow = lid & 15, quad = lid >> 4;
    const int m0 = blockIdx.y * 128, n0 = blockIdx.x * 128;

    const bf16* Ag = A   + (size_t)m0 * D_;
    const bf16* Bg = WpT + (size_t)n0 * D_;

    const int row0 = t >> 2, k80 = (t & 3) << 3;
    const int row1 = (t + 256) >> 2;

    f32x4 acc[4][4] = {};

    for (int k0 = 0; k0 < D_; k0 += 32) {
        __syncthreads();
        __builtin_amdgcn_global_load_lds(GLB(Ag + (size_t)row0 * D_ + k0 + k80),
                                         LDS(As + t * 8), 16, 0, 0);
        __builtin_amdgcn_global_load_lds(GLB(Bg + (size_t)row0 * D_ + k0 + k80),
                                         LDS(Bs + t * 8), 16, 0, 0);
        __builtin_amdgcn_global_load_lds(GLB(Ag + (size_t)row1 * D_ + k0 + k80),
                                         LDS(As + t * 8 + 2048), 16, 0, 0);
        __builtin_amdgcn_global_load_lds(GLB(Bg + (size_t)row1 * D_ + k0 + k80),
                                         LDS(Bs + t * 8 + 2048), 16, 0, 0);
        __syncthreads();
        bf16x8 a[4], b[4];
        #pragma unroll
        for (int mb = 0; mb < 4; ++mb)
            a[mb] = *(const bf16x8*)(As + (wm * 64 + mb * 16 + lrow) * 32 + quad * 8);
        #pragma unroll
        for (int nb = 0; nb < 4; ++nb)
            b[nb] = *(const bf16x8*)(Bs + (wn * 64 + nb * 16 + lrow) * 32 + quad * 8);
        #pragma unroll
        for (int mb = 0; mb < 4; ++mb)
            #pragma unroll
            for (int nb = 0; nb < 4; ++nb)
                acc[mb][nb] = __builtin_amdgcn_mfma_f32_16x16x32_bf16(b[nb], a[mb], acc[mb][nb], 0, 0, 0);
    }

    // epilogue: col=lane&15 -> m (row), reg r -> 4 consecutive n (cols)
    #pragma unroll
    for (int mb = 0; mb < 4; ++mb) {
        int gm = m0 + wm * 64 + mb * 16 + lrow;
        #pragma unroll
        for (int nb = 0; nb < 4; ++nb) {
            int gn0 = n0 + wn * 64 + nb * 16 + quad * 4;
            f32x4 bv4 = *(const f32x4*)(bp + gn0);
            f32x4 v = acc[mb][nb] + bv4;
            *(f32x4*)(out + (size_t)gm * D_ + gn0) = v;
        }
    }
}

// ---------------- launch ----------------
extern "C" void kernel_launch(void* const* d_in, const int* in_sizes, int n_in,
                              void* d_out, int out_size, void* d_ws, size_t ws_size,
                              hipStream_t stream)
{
    const float* x  = (const float*)d_in[0];
    const float* Wq = (const float*)d_in[1];
    const float* bq = (const float*)d_in[2];
    const float* Wk = (const float*)d_in[3];
    const float* bk = (const float*)d_in[4];
    const float* Wv = (const float*)d_in[5];
    const float* bv = (const float*)d_in[6];
    const float* Wp = (const float*)d_in[7];
    const float* bp = (const float*)d_in[8];

    bf16* ws = (bf16*)d_ws;
    const size_t WSZ = (size_t)D_ * D_;        // 1,048,576 elems
    const size_t BIG = (size_t)B_ * S_ * D_;   // 8,388,608 elems
    bf16* WqT = ws;
    bf16* WkT = WqT + WSZ;
    bf16* WvT = WkT + WSZ;
    bf16* WpT = WvT + WSZ;
    bf16* Qb  = WpT + WSZ;
    bf16* Kb  = Qb + BIG;
    bf16* Vb  = Kb + BIG;    // V^T layout [b,h,hd,s]
    bf16* Ab  = Vb + BIG;    // X(bf16) during qkv, then attention output

    transpose_cvt<<<dim3(32, 32, 4), 256, 0, stream>>>(
        Wq, Wk, Wv, Wp, WqT, WkT, WvT, WpT);

    cvt_x<<<dim3(4096), 256, 0, stream>>>(x, Ab);

    qkv_gemm<<<dim3(8, 64, 3), 256, 0, stream>>>(
        Ab, WqT, WkT, WvT, bq, bk, bv, Qb, Kb, Vb);

    attn_fwd<<<dim3(16, 64), 256, 0, stream>>>(Qb, Kb, Vb, Ab);

    proj_gemm<<<dim3(8, 64), 256, 0, stream>>>(Ab, WpT, bp, (float*)d_out);
}